// Round 8
// baseline (3541.533 us; speedup 1.0000x reference)
//
#include <hip/hip_runtime.h>

#define Nn 8192
#define Bb 4
#define KK 20
#define OO 64
#define EPSF 1e-5f
#define SLOPEF 0.2f

#define NBUCK 56
#define CAP 80                // E[C]~26-35; exact fallback covers overflow
#define BOFF 476              // (bits(2^-8) >> 21)
#define CLO 0.00390625f       // 2^-8
#define CHI 63.9999961853f    // largest float < 64 -> bucket <= 55
#define XBINS 256
#define XSCALE 25.6f          // bins over x in [-5, 5]
#define XOFF 5.0f

// ---------------- counting sort by x-bin: sx (sorted float4), ord (sorted->orig), cum -------

__global__ __launch_bounds__(1024) void sort_kernel(const float* __restrict__ x,
                                                    float4* __restrict__ sx,
                                                    int* __restrict__ ord,
                                                    int* __restrict__ cumg) {
  __shared__ unsigned hcnt[XBINS];
  __shared__ unsigned base[XBINS];
  __shared__ unsigned char binb[Nn];
  const int b = blockIdx.x;
  const float* xb = x + b * 3 * Nn;
  for (int t = threadIdx.x; t < XBINS; t += 1024) hcnt[t] = 0u;
  __syncthreads();
  for (int j = threadIdx.x; j < Nn; j += 1024) {
    float a0 = xb[j];
    int bin = (int)((a0 + XOFF) * XSCALE);               // monotone in x (trunc is monotone)
    bin = bin < 0 ? 0 : (bin > XBINS - 1 ? XBINS - 1 : bin);
    binb[j] = (unsigned char)bin;
    atomicAdd(&hcnt[bin], 1u);
  }
  __syncthreads();
  if (threadIdx.x == 0) {
    unsigned run = 0;
    for (int i = 0; i < XBINS; ++i) {
      base[i] = run;
      cumg[b * (XBINS + 1) + i] = (int)run;
      run += hcnt[i];
    }
    cumg[b * (XBINS + 1) + XBINS] = (int)run;            // = 8192
  }
  __syncthreads();
  for (int j = threadIdx.x; j < Nn; j += 1024) {
    float a0 = xb[j], a1 = xb[Nn + j], a2 = xb[2 * Nn + j];
    unsigned slot = atomicAdd(&base[binb[j]], 1u);       // in-bin order arbitrary (keys carry
    sx[b * Nn + slot] = make_float4(a0, a1, a2, a0 * a0 + a1 * a1 + a2 * a2);
    ord[b * Nn + slot] = j;                              //  orig idx -> order-independent)
  }
}

// ---------------- KNN: exact top-20 via x-window pruning + histogram threshold --------------
// lane = sorted row s; 16 waves/block. P1: histogram 512 x-adjacent points (any subset gives
// a valid upper bound T; x-near makes it tight). Window [cum[bin(x-rT)], cum[bin(x+rT)+1])
// provably contains every d<T point (d >= dx^2). P2 scans the block-union window split
// across 16 waves; keys = (sortable-dist-bits << 32) | ORIGINAL index -> (d, idx)-lex order
// == jax top_k tie-break, storage-order independent. Distance formula is bit-identical to
// the R4-R6 passing kernels. Anomalies (cnt<KK clamp edge, cnt>CAP) -> exact brute force.

__global__ __launch_bounds__(1024, 8) void knn_kernel(const float4* __restrict__ sx,
                                                      const int* __restrict__ ord,
                                                      const int* __restrict__ cumg,
                                                      int* __restrict__ idx_out) {
  __shared__ unsigned long long cdk[CAP * 64];   // [c][lane] 40960 B
  __shared__ unsigned hist[NBUCK * 64];          // [bk][lane] 14336 B
  __shared__ unsigned ccnt[64];
  __shared__ int wlo_sh, whi_sh;

  const int lane = threadIdx.x & 63;
  const int wid  = __builtin_amdgcn_readfirstlane(threadIdx.x >> 6);
  const int b    = blockIdx.y;
  const int s    = blockIdx.x * 64 + lane;       // sorted row index

  for (int t = threadIdx.x; t < NBUCK * 64; t += 1024) hist[t] = 0u;
  if (threadIdx.x < 64) ccnt[threadIdx.x] = 0u;
  if (threadIdx.x == 0) { wlo_sh = Nn; whi_sh = 0; }

  const float4* __restrict__ sxb  = sx + b * Nn;
  const int*    __restrict__ ordb = ord + b * Nn;
  const float4 me = sxb[s];
  unsigned* hrow0 = &hist[lane] - (BOFF << 6);

  __syncthreads();

  // ---- P1: histogram the 512 sorted points centered on this block ----
  int sub0 = blockIdx.x * 64 + 32 - 256;
  sub0 = sub0 < 0 ? 0 : (sub0 > Nn - 512 ? Nn - 512 : sub0);
  {
    const float4* seg = sxb + sub0 + wid * 32;
    for (int j = 0; j < 32; j += 4) {
      #pragma unroll
      for (int t = 0; t < 4; ++t) {
        float4 p = seg[j + t];
        float inner = fmaf(p.x, me.x, fmaf(p.y, me.y, p.z * me.z));
        float d  = fmaf(-2.0f, inner, me.w + p.w);
        float dc = __builtin_amdgcn_fmed3f(d, CLO, CHI);
        atomicAdd(hrow0 + ((__float_as_uint(dc) >> 21) << 6), 1u);
      }
    }
  }
  __syncthreads();

  // ---- threshold + window ----
  unsigned cum = 0; int crit = 0;
  #pragma unroll 1
  for (int t = 0; t < NBUCK; ++t) {
    cum += hist[t * 64 + lane];
    crit += (cum < KK) ? 1 : 0;
  }
  const float Tup = __uint_as_float((unsigned)(BOFF + crit + 1) << 21);
  float rT = sqrtf(Tup);
  rT = __uint_as_float(__float_as_uint(rT) + 2);         // +2 ulp: never lose a boundary point
  {
    int blo = (int)((me.x - rT + XOFF) * XSCALE);
    blo = blo < 0 ? 0 : (blo > XBINS - 1 ? XBINS - 1 : blo);
    int bhi = (int)((me.x + rT + XOFF) * XSCALE);
    bhi = bhi < 0 ? 0 : (bhi > XBINS - 1 ? XBINS - 1 : bhi);
    atomicMin(&wlo_sh, cumg[b * (XBINS + 1) + blo]);
    atomicMax(&whi_sh, cumg[b * (XBINS + 1) + bhi + 1]);
  }
  __syncthreads();

  // ---- P2: scan block-union window, split across 16 waves ----
  const int Blo = wlo_sh, Bhi = whi_sh;
  const int per = ((Bhi - Blo) + 15) >> 4;
  int lo = Blo + wid * per;
  int hi = lo + per; hi = hi > Bhi ? Bhi : hi;
  for (int j0 = lo; j0 < hi; j0 += 4) {
    float d[4]; bool a[4];
    #pragma unroll
    for (int t = 0; t < 4; ++t) {
      float4 p = sxb[j0 + t];                            // tail over-read guarded below
      float inner = fmaf(p.x, me.x, fmaf(p.y, me.y, p.z * me.z));
      d[t] = fmaf(-2.0f, inner, me.w + p.w);
      a[t] = (d[t] < Tup) && (j0 + t < hi);
    }
    if (__any(a[0] | a[1] | a[2] | a[3])) {
      #pragma unroll
      for (int t = 0; t < 4; ++t) {
        if (a[t]) {
          unsigned oj = (unsigned)ordb[j0 + t];          // wave-uniform -> scalar load
          int bb = (int)__float_as_uint(d[t]);
          unsigned sk = (unsigned)(bb ^ ((bb >> 31) | 0x80000000));  // float -> sortable
          unsigned c = atomicAdd(&ccnt[lane], 1u);
          if (c < CAP)
            cdk[c * 64 + lane] = ((unsigned long long)sk << 32) | oj;
        }
      }
    }
  }
  __syncthreads();

  // ---- P3: wave-parallel rank selection (keys distinct via orig idx) ----
  const unsigned cnt = ccnt[lane];
  const bool bad = (cnt < KK) || (cnt > CAP);
  const int C = (int)(cnt < CAP ? cnt : CAP);
  const int n = ordb[s];                                 // original row id
  int* op = idx_out + (b * Nn + n) * KK;
  for (int c = wid; __any(c < C); c += 16) {
    if (c < C) {
      unsigned long long key = cdk[c * 64 + lane];
      int rank = 0;
      for (int c2 = 0; __any(c2 < C); ++c2)
        rank += (c2 < C && cdk[c2 * 64 + lane] < key) ? 1 : 0;
      if (rank < KK && !bad)
        op[rank] = (int)(key & 0xFFFFFFFFu);
    }
  }
  // ---- exact fallback for anomalous rows ----
  if (wid == 0 && __any(bad)) {
    if (bad) {
      unsigned long long q[KK];
      #pragma unroll
      for (int k = 0; k < KK; ++k) q[k] = ~0ULL;
      #pragma unroll 1
      for (int j = 0; j < Nn; ++j) {
        float4 p = sxb[j];
        float inner = fmaf(p.x, me.x, fmaf(p.y, me.y, p.z * me.z));
        float dd = fmaf(-2.0f, inner, me.w + p.w);
        int bb = (int)__float_as_uint(dd);
        unsigned sk = (unsigned)(bb ^ ((bb >> 31) | 0x80000000));
        unsigned long long key = ((unsigned long long)sk << 32) | (unsigned)ordb[j];
        if (key < q[KK - 1]) {
          #pragma unroll
          for (int k = 0; k < KK; ++k) {
            bool sw = key < q[k];
            unsigned long long tq = q[k];
            q[k] = sw ? key : tq;
            key  = sw ? tq : key;
          }
        }
      }
      #pragma unroll
      for (int k = 0; k < KK; ++k) op[k] = (int)(q[k] & 0xFFFFFFFFu);
    }
  }
}

// ---------------- u = (Wa-Wb)·x_n, v = Wb·x_n  (layout [b][n][o], o contiguous) -------------

__global__ __launch_bounds__(256) void uv_kernel(const float* __restrict__ x,
                                                 const float* __restrict__ W,
                                                 float* __restrict__ u,
                                                 float* __restrict__ v) {
  int gid = blockIdx.x * 256 + threadIdx.x;
  int o  = gid & 63;
  int bn = gid >> 6;
  int b  = bn >> 13;
  int n  = bn & (Nn - 1);
  const float* xb = x + b * 3 * Nn;
  float x0 = xb[n], x1 = xb[Nn + n], x2 = xb[2 * Nn + n];
  float wa0 = W[o * 6 + 0], wa1 = W[o * 6 + 1], wa2 = W[o * 6 + 2];
  float wb0 = W[o * 6 + 3], wb1 = W[o * 6 + 4], wb2 = W[o * 6 + 5];
  u[gid] = (wa0 - wb0) * x0 + (wa1 - wb1) * x1 + (wa2 - wb2) * x2;
  v[gid] = wb0 * x0 + wb1 * x1 + wb2 * x2;
}

// ---------------- gather v over neighbors: pm = u + max_k v ; accumulate S1,S2 --------------

__global__ __launch_bounds__(256) void gather_kernel(const int* __restrict__ idx,
                                                     float* __restrict__ u,      // in-place -> pm
                                                     const float* __restrict__ v,
                                                     float* __restrict__ stats) {
  __shared__ float ls1[4][64], ls2[4][64];
  int b  = blockIdx.y;
  int o  = threadIdx.x & 63;
  int ys = threadIdx.x >> 6;
  const float* vb = v + (size_t)b * Nn * OO;
  float s1 = 0.f, s2 = 0.f;
  for (int i = 0; i < 16; ++i) {
    int n = blockIdx.x * 64 + ys * 16 + i;
    const int* ip = idx + (b * Nn + n) * KK;
    float un = u[(size_t)(b * Nn + n) * OO + o];
    float sv = 0.f, sv2 = 0.f, mv = -__builtin_inff();
    #pragma unroll
    for (int k = 0; k < KK; ++k) {
      int j = ip[k];
      float val = vb[(size_t)j * OO + o];
      sv += val; sv2 += val * val; mv = fmaxf(mv, val);
    }
    u[(size_t)(b * Nn + n) * OO + o] = un + mv;
    s1 += (float)KK * un + sv;
    s2 += (float)KK * un * un + 2.f * un * sv + sv2;
  }
  ls1[ys][o] = s1; ls2[ys][o] = s2;
  __syncthreads();
  if (ys == 0) {
    float t1 = ls1[0][o] + ls1[1][o] + ls1[2][o] + ls1[3][o];
    float t2 = ls2[0][o] + ls2[1][o] + ls2[2][o] + ls2[3][o];
    atomicAdd(&stats[(b * OO + o) * 2 + 0], t1);
    atomicAdd(&stats[(b * OO + o) * 2 + 1], t2);
  }
}

// ---------------- finalize: normalize + lrelu + transpose to [b][o][n] ----------------------

__global__ __launch_bounds__(256) void out_kernel(const float* __restrict__ pm,
                                                  const float* __restrict__ stats,
                                                  float* __restrict__ out) {
  __shared__ float tile[64][65];
  int b  = blockIdx.y;
  int o  = threadIdx.x & 63;
  int ys = threadIdx.x >> 6;
  const float inv_cnt = 1.0f / (float)(Nn * KK);
  float S1 = stats[(b * OO + o) * 2 + 0];
  float S2 = stats[(b * OO + o) * 2 + 1];
  float mean = S1 * inv_cnt;
  float var  = S2 * inv_cnt - mean * mean;
  float istd = rsqrtf(var + EPSF);
  for (int i = 0; i < 16; ++i) {
    int n = blockIdx.x * 64 + ys * 16 + i;
    float val = (pm[(size_t)(b * Nn + n) * OO + o] - mean) * istd;
    val = (val >= 0.f) ? val : SLOPEF * val;
    tile[ys * 16 + i][o] = val;
  }
  __syncthreads();
  int nb = blockIdx.x * 64;
  for (int i = 0; i < 16; ++i) {
    int oo = ys * 16 + i;
    out[(size_t)(b * OO + oo) * Nn + nb + o] = tile[o][oo];
  }
}

// ---------------- launch ---------------------------------------------------------------------

extern "C" void kernel_launch(void* const* d_in, const int* in_sizes, int n_in,
                              void* d_out, int out_size, void* d_ws, size_t ws_size,
                              hipStream_t stream) {
  const float* x = (const float*)d_in[0];
  const float* W = (const float*)d_in[1];
  float* out = (float*)d_out;

  char* ws = (char*)d_ws;
  int*    idx   = (int*)ws;                         // 2,621,440 B
  float*  u     = (float*)(ws + 2621440);           // 8,388,608 B (becomes pm)
  float*  v     = (float*)(ws + 11010048);          // 8,388,608 B
  float*  stats = (float*)(ws + 19398656);          // 4,096 B
  float4* sx    = (float4*)(ws + 19402752);         // 524,288 B (16B aligned)
  int*    ord   = (int*)(ws + 19927040);            // 131,072 B
  int*    cumg  = (int*)(ws + 20058112);            // 4,112 B

  hipMemsetAsync(stats, 0, Bb * OO * 2 * sizeof(float), stream);
  sort_kernel  <<<Bb, 1024, 0, stream>>>(x, sx, ord, cumg);
  uv_kernel    <<<dim3((Bb * Nn * OO) / 256), 256, 0, stream>>>(x, W, u, v);
  knn_kernel   <<<dim3(128, Bb), 1024, 0, stream>>>(sx, ord, cumg, idx);
  gather_kernel<<<dim3(128, Bb), 256, 0, stream>>>(idx, u, v, stats);
  out_kernel   <<<dim3(128, Bb), 256, 0, stream>>>(u, stats, out);
}

// Round 9
// 279.899 us; speedup vs baseline: 12.6529x; 12.6529x over previous
//
#include <hip/hip_runtime.h>

#define Nn 8192
#define Bb 4
#define KK 20
#define OO 64
#define EPSF 1e-5f
#define SLOPEF 0.2f

#define NBUCK 56
#define CAP 80                // E[cnt]~20-26 after fine refinement; fallback covers tails
#define BOFF 476              // (bits(2^-8) >> 21)
#define CLO 0.00390625f       // 2^-8
#define CHI 63.9999961853f    // largest float < 64 -> coarse bucket <= 55
#define XBINS 256
#define XSCALE 25.6f          // bins over x in [-5, 5]
#define XOFF 5.0f

// ---------------- counting sort by x-bin: sx (sorted float4), ord (sorted->orig), cum -------

__global__ __launch_bounds__(1024) void sort_kernel(const float* __restrict__ x,
                                                    float4* __restrict__ sx,
                                                    int* __restrict__ ord,
                                                    int* __restrict__ cumg) {
  __shared__ unsigned hcnt[XBINS];
  __shared__ unsigned base[XBINS];
  __shared__ unsigned char binb[Nn];
  const int b = blockIdx.x;
  const float* xb = x + b * 3 * Nn;
  for (int t = threadIdx.x; t < XBINS; t += 1024) hcnt[t] = 0u;
  __syncthreads();
  for (int j = threadIdx.x; j < Nn; j += 1024) {
    float a0 = xb[j];
    int bin = (int)((a0 + XOFF) * XSCALE);               // monotone in x
    bin = bin < 0 ? 0 : (bin > XBINS - 1 ? XBINS - 1 : bin);
    binb[j] = (unsigned char)bin;
    atomicAdd(&hcnt[bin], 1u);
  }
  __syncthreads();
  if (threadIdx.x == 0) {
    unsigned run = 0;
    #pragma unroll 8
    for (int i = 0; i < XBINS; ++i) {
      base[i] = run;
      cumg[b * (XBINS + 1) + i] = (int)run;
      run += hcnt[i];
    }
    cumg[b * (XBINS + 1) + XBINS] = (int)run;            // = 8192
  }
  __syncthreads();
  for (int j = threadIdx.x; j < Nn; j += 1024) {
    float a0 = xb[j], a1 = xb[Nn + j], a2 = xb[2 * Nn + j];
    unsigned slot = atomicAdd(&base[binb[j]], 1u);       // in-bin order arbitrary (keys carry
    sx[b * Nn + slot] = make_float4(a0, a1, a2, a0 * a0 + a1 * a1 + a2 * a2);
    ord[b * Nn + slot] = j;                              //  orig idx -> order-independent)
  }
}

// ---------------- KNN: exact top-20, x-window pruning + two-level histogram select ----------
// lane = sorted row s; 16 waves/block. P1: coarse exponent-bucket histogram of 512 x-near
// points -> valid upper bound Tup (loose ~2x for central rows: thin-slab geometry) and the
// window [cum[bin(x-rT)], cum[bin(x+rT)+1]) which provably holds every d<Tup point (d>=dx^2).
// P1.5: re-zero hist; fine LINEAR histogram of window points over [0,Tup) -> crit2.
// P2: accept via the bit-identical quantization bk(d)<=crit2 -> cnt in [20,~26].
// EXACTNESS (independent of threshold quality): bk is monotone in d, so if cnt>=20 points
// satisfy bk<=crit2, any point p with bk_p>crit2 has >=20 points at d<=d_p (strictly < or
// equal-d with same bk), hence p is not in the top-20 under any tie-break. cnt<KK, cnt>CAP,
// or coarse clamp-top (crit>=55) -> exec-masked exact brute-force fallback (never taken).

__global__ __launch_bounds__(1024, 8) void knn_kernel(const float4* __restrict__ sx,
                                                      const int* __restrict__ ord,
                                                      const int* __restrict__ cumg,
                                                      int* __restrict__ idx_out) {
  __shared__ unsigned long long cdk[CAP * 64];   // [c][lane] 40960 B
  __shared__ unsigned hist[NBUCK * 64];          // [bk][lane] 14336 B
  __shared__ unsigned ccnt[64];
  __shared__ int wlo_sh, whi_sh;

  const int lane = threadIdx.x & 63;
  const int wid  = __builtin_amdgcn_readfirstlane(threadIdx.x >> 6);
  const int b    = blockIdx.y;
  const int s    = blockIdx.x * 64 + lane;       // sorted row index

  for (int t = threadIdx.x; t < NBUCK * 64; t += 1024) hist[t] = 0u;
  if (threadIdx.x < 64) ccnt[threadIdx.x] = 0u;
  if (threadIdx.x == 0) { wlo_sh = Nn; whi_sh = 0; }

  const float4* __restrict__ sxb  = sx + b * Nn;
  const int*    __restrict__ ordb = ord + b * Nn;
  const float4 me = sxb[s];
  unsigned* hrow0 = &hist[lane] - (BOFF << 6);

  __syncthreads();

  // ---- P1: coarse histogram of the 512 sorted points centered on this block ----
  int sub0 = blockIdx.x * 64 + 32 - 256;
  sub0 = sub0 < 0 ? 0 : (sub0 > Nn - 512 ? Nn - 512 : sub0);
  {
    const float4* seg = sxb + sub0 + wid * 32;
    for (int j = 0; j < 32; j += 4) {
      #pragma unroll
      for (int t = 0; t < 4; ++t) {
        float4 p = seg[j + t];
        float inner = fmaf(p.x, me.x, fmaf(p.y, me.y, p.z * me.z));
        float d  = fmaf(-2.0f, inner, me.w + p.w);
        float dc = __builtin_amdgcn_fmed3f(d, CLO, CHI);
        atomicAdd(hrow0 + ((__float_as_uint(dc) >> 21) << 6), 1u);
      }
    }
  }
  __syncthreads();

  // ---- coarse scan -> Tup, window union ----
  unsigned cum = 0; int crit = 0;
  #pragma unroll 1
  for (int t = 0; t < NBUCK; ++t) {
    cum += hist[t * 64 + lane];
    crit += (cum < KK) ? 1 : 0;
  }
  const float Tup = __uint_as_float((unsigned)(BOFF + crit + 1) << 21);
  float rT = sqrtf(Tup);
  rT = __uint_as_float(__float_as_uint(rT) + 2);         // +2 ulp: never lose a boundary point
  {
    int blo = (int)((me.x - rT + XOFF) * XSCALE);
    blo = blo < 0 ? 0 : (blo > XBINS - 1 ? XBINS - 1 : blo);
    int bhi = (int)((me.x + rT + XOFF) * XSCALE);
    bhi = bhi < 0 ? 0 : (bhi > XBINS - 1 ? XBINS - 1 : bhi);
    atomicMin(&wlo_sh, cumg[b * (XBINS + 1) + blo]);
    atomicMax(&whi_sh, cumg[b * (XBINS + 1) + bhi + 1]);
  }
  __syncthreads();                                        // scans done, window final

  const int Blo = wlo_sh, Bhi = whi_sh;
  const int per = ((Bhi - Blo) + 15) >> 4;
  const int lo = Blo + wid * per;
  const int hiq = lo + per;
  const int hi = hiq > Bhi ? Bhi : hiq;

  // ---- re-zero hist for the fine pass ----
  for (int t = threadIdx.x; t < NBUCK * 64; t += 1024) hist[t] = 0u;
  __syncthreads();

  // ---- P1.5: fine linear histogram over [0, Tup) on the window slice ----
  const float s56 = 56.0f / Tup;
  for (int j0 = lo; j0 < hi; j0 += 4) {
    #pragma unroll
    for (int t = 0; t < 4; ++t) {
      float4 p = sxb[j0 + t];                            // tail over-read guarded below
      float inner = fmaf(p.x, me.x, fmaf(p.y, me.y, p.z * me.z));
      float d = fmaf(-2.0f, inner, me.w + p.w);
      int bk = (int)(d * s56);
      if ((unsigned)bk < (unsigned)NBUCK && (j0 + t) < hi)
        atomicAdd(&hist[(bk << 6) + lane], 1u);
    }
  }
  __syncthreads();

  // ---- fine scan -> crit2 ----
  unsigned cum2 = 0; int crit2 = 0;
  #pragma unroll 1
  for (int t = 0; t < NBUCK; ++t) {
    cum2 += hist[t * 64 + lane];
    crit2 += (cum2 < KK) ? 1 : 0;
  }

  // ---- P2: collect candidates with bk(d) <= crit2 (bit-identical quantization) ----
  for (int j0 = lo; j0 < hi; j0 += 4) {
    #pragma unroll
    for (int t = 0; t < 4; ++t) {
      float4 p = sxb[j0 + t];
      float inner = fmaf(p.x, me.x, fmaf(p.y, me.y, p.z * me.z));
      float d = fmaf(-2.0f, inner, me.w + p.w);
      int bk = (int)(d * s56);
      if (bk <= crit2 && (j0 + t) < hi) {
        unsigned oj = (unsigned)ordb[j0 + t];            // wave-uniform -> scalar load
        int bb = (int)__float_as_uint(d);
        unsigned sk = (unsigned)(bb ^ ((bb >> 31) | 0x80000000));  // float -> sortable
        unsigned c = atomicAdd(&ccnt[lane], 1u);
        if (c < CAP)
          cdk[c * 64 + lane] = ((unsigned long long)sk << 32) | oj;
      }
    }
  }
  __syncthreads();

  // ---- P3: wave-parallel rank selection (keys distinct via orig idx) ----
  const unsigned cnt = ccnt[lane];
  const bool bad = (cnt < KK) || (cnt > CAP) || (crit >= NBUCK - 1);
  const int C = (int)(cnt < CAP ? cnt : CAP);
  const int n = ordb[s];                                 // original row id
  int* op = idx_out + (b * Nn + n) * KK;
  for (int c = wid; __any(c < C); c += 16) {
    if (c < C) {
      unsigned long long key = cdk[c * 64 + lane];
      int rank = 0;
      for (int c2 = 0; __any(c2 < C); ++c2)
        rank += (c2 < C && cdk[c2 * 64 + lane] < key) ? 1 : 0;
      if (rank < KK && !bad)
        op[rank] = (int)(key & 0xFFFFFFFFu);
    }
  }
  // ---- exact fallback for anomalous rows (measure-zero after refinement) ----
  if (wid == 0 && __any(bad)) {
    if (bad) {
      unsigned long long q[KK];
      #pragma unroll
      for (int k = 0; k < KK; ++k) q[k] = ~0ULL;
      #pragma unroll 1
      for (int j = 0; j < Nn; ++j) {
        float4 p = sxb[j];
        float inner = fmaf(p.x, me.x, fmaf(p.y, me.y, p.z * me.z));
        float dd = fmaf(-2.0f, inner, me.w + p.w);
        int bb = (int)__float_as_uint(dd);
        unsigned sk = (unsigned)(bb ^ ((bb >> 31) | 0x80000000));
        unsigned long long key = ((unsigned long long)sk << 32) | (unsigned)ordb[j];
        if (key < q[KK - 1]) {
          #pragma unroll
          for (int k = 0; k < KK; ++k) {
            bool sw = key < q[k];
            unsigned long long tq = q[k];
            q[k] = sw ? key : tq;
            key  = sw ? tq : key;
          }
        }
      }
      #pragma unroll
      for (int k = 0; k < KK; ++k) op[k] = (int)(q[k] & 0xFFFFFFFFu);
    }
  }
}

// ---------------- u = (Wa-Wb)·x_n, v = Wb·x_n  (layout [b][n][o], o contiguous) -------------

__global__ __launch_bounds__(256) void uv_kernel(const float* __restrict__ x,
                                                 const float* __restrict__ W,
                                                 float* __restrict__ u,
                                                 float* __restrict__ v) {
  int gid = blockIdx.x * 256 + threadIdx.x;
  int o  = gid & 63;
  int bn = gid >> 6;
  int b  = bn >> 13;
  int n  = bn & (Nn - 1);
  const float* xb = x + b * 3 * Nn;
  float x0 = xb[n], x1 = xb[Nn + n], x2 = xb[2 * Nn + n];
  float wa0 = W[o * 6 + 0], wa1 = W[o * 6 + 1], wa2 = W[o * 6 + 2];
  float wb0 = W[o * 6 + 3], wb1 = W[o * 6 + 4], wb2 = W[o * 6 + 5];
  u[gid] = (wa0 - wb0) * x0 + (wa1 - wb1) * x1 + (wa2 - wb2) * x2;
  v[gid] = wb0 * x0 + wb1 * x1 + wb2 * x2;
}

// ---------------- gather v over neighbors: pm = u + max_k v ; accumulate S1,S2 --------------

__global__ __launch_bounds__(256) void gather_kernel(const int* __restrict__ idx,
                                                     float* __restrict__ u,      // in-place -> pm
                                                     const float* __restrict__ v,
                                                     float* __restrict__ stats) {
  __shared__ float ls1[4][64], ls2[4][64];
  int b  = blockIdx.y;
  int o  = threadIdx.x & 63;
  int ys = threadIdx.x >> 6;
  const float* vb = v + (size_t)b * Nn * OO;
  float s1 = 0.f, s2 = 0.f;
  for (int i = 0; i < 16; ++i) {
    int n = blockIdx.x * 64 + ys * 16 + i;
    const int* ip = idx + (b * Nn + n) * KK;
    float un = u[(size_t)(b * Nn + n) * OO + o];
    float sv = 0.f, sv2 = 0.f, mv = -__builtin_inff();
    #pragma unroll
    for (int k = 0; k < KK; ++k) {
      int j = ip[k];
      float val = vb[(size_t)j * OO + o];
      sv += val; sv2 += val * val; mv = fmaxf(mv, val);
    }
    u[(size_t)(b * Nn + n) * OO + o] = un + mv;
    s1 += (float)KK * un + sv;
    s2 += (float)KK * un * un + 2.f * un * sv + sv2;
  }
  ls1[ys][o] = s1; ls2[ys][o] = s2;
  __syncthreads();
  if (ys == 0) {
    float t1 = ls1[0][o] + ls1[1][o] + ls1[2][o] + ls1[3][o];
    float t2 = ls2[0][o] + ls2[1][o] + ls2[2][o] + ls2[3][o];
    atomicAdd(&stats[(b * OO + o) * 2 + 0], t1);
    atomicAdd(&stats[(b * OO + o) * 2 + 1], t2);
  }
}

// ---------------- finalize: normalize + lrelu + transpose to [b][o][n] ----------------------

__global__ __launch_bounds__(256) void out_kernel(const float* __restrict__ pm,
                                                  const float* __restrict__ stats,
                                                  float* __restrict__ out) {
  __shared__ float tile[64][65];
  int b  = blockIdx.y;
  int o  = threadIdx.x & 63;
  int ys = threadIdx.x >> 6;
  const float inv_cnt = 1.0f / (float)(Nn * KK);
  float S1 = stats[(b * OO + o) * 2 + 0];
  float S2 = stats[(b * OO + o) * 2 + 1];
  float mean = S1 * inv_cnt;
  float var  = S2 * inv_cnt - mean * mean;
  float istd = rsqrtf(var + EPSF);
  for (int i = 0; i < 16; ++i) {
    int n = blockIdx.x * 64 + ys * 16 + i;
    float val = (pm[(size_t)(b * Nn + n) * OO + o] - mean) * istd;
    val = (val >= 0.f) ? val : SLOPEF * val;
    tile[ys * 16 + i][o] = val;
  }
  __syncthreads();
  int nb = blockIdx.x * 64;
  for (int i = 0; i < 16; ++i) {
    int oo = ys * 16 + i;
    out[(size_t)(b * OO + oo) * Nn + nb + o] = tile[o][oo];
  }
}

// ---------------- launch ---------------------------------------------------------------------

extern "C" void kernel_launch(void* const* d_in, const int* in_sizes, int n_in,
                              void* d_out, int out_size, void* d_ws, size_t ws_size,
                              hipStream_t stream) {
  const float* x = (const float*)d_in[0];
  const float* W = (const float*)d_in[1];
  float* out = (float*)d_out;

  char* ws = (char*)d_ws;
  int*    idx   = (int*)ws;                         // 2,621,440 B
  float*  u     = (float*)(ws + 2621440);           // 8,388,608 B (becomes pm)
  float*  v     = (float*)(ws + 11010048);          // 8,388,608 B
  float*  stats = (float*)(ws + 19398656);          // 4,096 B
  float4* sx    = (float4*)(ws + 19402752);         // 524,288 B (16B aligned)
  int*    ord   = (int*)(ws + 19927040);            // 131,072 B
  int*    cumg  = (int*)(ws + 20058112);            // 4,112 B

  hipMemsetAsync(stats, 0, Bb * OO * 2 * sizeof(float), stream);
  sort_kernel  <<<Bb, 1024, 0, stream>>>(x, sx, ord, cumg);
  uv_kernel    <<<dim3((Bb * Nn * OO) / 256), 256, 0, stream>>>(x, W, u, v);
  knn_kernel   <<<dim3(128, Bb), 1024, 0, stream>>>(sx, ord, cumg, idx);
  gather_kernel<<<dim3(128, Bb), 256, 0, stream>>>(idx, u, v, stats);
  out_kernel   <<<dim3(128, Bb), 256, 0, stream>>>(u, stats, out);
}

// Round 10
// 255.069 us; speedup vs baseline: 13.8846x; 1.0973x over previous
//
#include <hip/hip_runtime.h>

#define Nn 8192
#define Bb 4
#define KK 20
#define OO 64
#define EPSF 1e-5f
#define SLOPEF 0.2f

#define NBUCK 56
#define CAP 256               // per-row candidate list; refine loop handles overflow
#define BOFF 476              // (bits(2^-8) >> 21)
#define CLO 0.00390625f       // 2^-8
#define CHI 63.9999961853f    // largest float < 64 -> coarse bucket <= 55
#define XBINS 256
#define XSCALE 25.6f          // bins over x in [-5, 5]
#define XOFF 5.0f

// ---------------- counting sort by x-bin: sx (sorted float4), ord (sorted->orig), cum -------

__global__ __launch_bounds__(1024) void sort_kernel(const float* __restrict__ x,
                                                    float4* __restrict__ sx,
                                                    int* __restrict__ ord,
                                                    int* __restrict__ cumg) {
  __shared__ unsigned hcnt[XBINS];
  __shared__ unsigned base[XBINS];
  __shared__ unsigned char binb[Nn];
  const int b = blockIdx.x;
  const float* xb = x + b * 3 * Nn;
  for (int t = threadIdx.x; t < XBINS; t += 1024) hcnt[t] = 0u;
  __syncthreads();
  for (int j = threadIdx.x; j < Nn; j += 1024) {
    float a0 = xb[j];
    int bin = (int)((a0 + XOFF) * XSCALE);               // monotone in x
    bin = bin < 0 ? 0 : (bin > XBINS - 1 ? XBINS - 1 : bin);
    binb[j] = (unsigned char)bin;
    atomicAdd(&hcnt[bin], 1u);
  }
  __syncthreads();
  if (threadIdx.x == 0) {
    unsigned run = 0;
    #pragma unroll 8
    for (int i = 0; i < XBINS; ++i) {
      base[i] = run;
      cumg[b * (XBINS + 1) + i] = (int)run;
      run += hcnt[i];
    }
    cumg[b * (XBINS + 1) + XBINS] = (int)run;            // = 8192
  }
  __syncthreads();
  for (int j = threadIdx.x; j < Nn; j += 1024) {
    float a0 = xb[j], a1 = xb[Nn + j], a2 = xb[2 * Nn + j];
    unsigned slot = atomicAdd(&base[binb[j]], 1u);       // in-bin order arbitrary (keys carry
    sx[b * Nn + slot] = make_float4(a0, a1, a2, a0 * a0 + a1 * a1 + a2 * a2);
    ord[b * Nn + slot] = j;                              //  orig idx -> order-independent)
  }
}

// ---------------- KNN: exact top-20, ROW-PER-WAVE, x-window + histogram refinement ----------
// Wave = one sorted row; 16 rows/block; NO __syncthreads (per-wave LDS slices). 64 lanes
// split the row's own window (coalesced float4). P1: coarse exponent hist of 512 x-near ->
// valid upper bound Tup. Window [cum[bin(x-rT-eps)], cum[bin(x+rT+eps)+1]) provably holds
// every d<Tup point (d>=dx^2; eps=1e-5 absolute > all fp rounding; bin map monotone).
// Pass1: ballot-append keys (dist-bits, orig idx) for d<Tup. Overflow -> refine loop:
// fine linear hist on [0,Tup) over window -> crit2; if cum(crit2)<=CAP collect bk<=crit2
// (bit-identical quantization; monotone in d + cum>=KK  =>  accept-set contains true top-20);
// else tighten Tup=edge(crit2+1), shrink window, repeat. Ultimate (never expected): 20-round
// wave-min with strictly-increasing keys over the window. All paths exact + deterministic.

__global__ __launch_bounds__(1024, 8) void knn_kernel(const float4* __restrict__ sx,
                                                      const int* __restrict__ ord,
                                                      const int* __restrict__ cumg,
                                                      int* __restrict__ idx_out) {
  __shared__ unsigned hist[16][64];                 //  4096 B, per-wave slice
  __shared__ unsigned long long cdk[16][CAP];       // 32768 B, per-wave slice

  const int lane = threadIdx.x & 63;
  const int wid  = threadIdx.x >> 6;
  const int b    = blockIdx.y;
  const int r    = blockIdx.x * 16 + wid;           // sorted row index (wave-uniform)

  const float4* __restrict__ sxb  = sx + b * Nn;
  const int*    __restrict__ ordb = ord + b * Nn;
  const int*    __restrict__ cumb = cumg + b * (XBINS + 1);
  const float4 me = sxb[r];
  const unsigned long long below = (1ull << lane) - 1ull;

  hist[wid][lane] = 0u;

  // ---- P1: coarse hist of 512 x-near points ----
  int sub0 = r - 256; sub0 = sub0 < 0 ? 0 : (sub0 > Nn - 512 ? Nn - 512 : sub0);
  #pragma unroll
  for (int i = 0; i < 8; ++i) {
    float4 p = sxb[sub0 + i * 64 + lane];
    float inner = fmaf(p.x, me.x, fmaf(p.y, me.y, p.z * me.z));
    float d  = fmaf(-2.0f, inner, me.w + p.w);
    float dc = __builtin_amdgcn_fmed3f(d, CLO, CHI);
    atomicAdd(&hist[wid][(__float_as_uint(dc) >> 21) - BOFF], 1u);
  }
  // wave prefix-scan of the 56 buckets
  unsigned cum = (lane < NBUCK) ? hist[wid][lane] : 0u;
  #pragma unroll
  for (int off = 1; off < 64; off <<= 1) {
    unsigned o = __shfl_up(cum, off);
    if (lane >= off) cum += o;
  }
  int crit = __popcll(__ballot(lane < NBUCK && cum < KK));
  // crit>=55: bucket-55 holds clamped d>CHI -> invalid edge; fall back to huge Tup
  float Tup = (crit >= NBUCK - 1) ? 256.0f
                                  : __uint_as_float((unsigned)(BOFF + crit + 1) << 21);

  // ---- window from Tup (superset-safe: absolute 1e-5 slack > all rounding) ----
  float rT = sqrtf(Tup);
  int bn_ = (int)((me.x - rT - 1e-5f + XOFF) * XSCALE);
  bn_ = bn_ < 0 ? 0 : (bn_ > XBINS - 1 ? XBINS - 1 : bn_);
  int rlo = cumb[bn_];
  bn_ = (int)((me.x + rT + 1e-5f + XOFF) * XSCALE);
  bn_ = bn_ < 0 ? 0 : (bn_ > XBINS - 1 ? XBINS - 1 : bn_);
  int rhi = cumb[bn_ + 1];

  // ---- pass 1: collect d < Tup via ballot-append ----
  int cnt = 0;
  for (int j0 = rlo; j0 < rhi; j0 += 64) {
    int j = j0 + lane;
    bool acc = false; float d = 0.f;
    if (j < rhi) {
      float4 p = sxb[j];
      float inner = fmaf(p.x, me.x, fmaf(p.y, me.y, p.z * me.z));
      d = fmaf(-2.0f, inner, me.w + p.w);
      acc = d < Tup;
    }
    unsigned long long m = __ballot(acc);
    if (acc) {
      int slot = cnt + __popcll(m & below);
      if (slot < CAP) {
        int bb = (int)__float_as_uint(d);
        unsigned sk = (unsigned)(bb ^ ((bb >> 31) | 0x80000000));
        cdk[wid][slot] = ((unsigned long long)sk << 32) | (unsigned)ordb[j];
      }
    }
    cnt += __popcll(m);
    if (cnt > CAP) break;                     // exact cnt beyond CAP irrelevant
  }

  // ---- refine loop (rare: y,z-outlier rows where slab Tup is loose) ----
  for (int it = 0; cnt > CAP && it < 4; ++it) {
    hist[wid][lane] = 0u;
    const float s56 = 56.0f / Tup;
    for (int j0 = rlo; j0 < rhi; j0 += 64) {
      int j = j0 + lane;
      if (j < rhi) {
        float4 p = sxb[j];
        float inner = fmaf(p.x, me.x, fmaf(p.y, me.y, p.z * me.z));
        float d = fmaf(-2.0f, inner, me.w + p.w);
        int bk = (int)(d * s56);              // d<0 (self, fp) -> 0 via trunc
        if ((unsigned)bk < (unsigned)NBUCK) atomicAdd(&hist[wid][bk], 1u);
      }
    }
    unsigned cum2 = (lane < NBUCK) ? hist[wid][lane] : 0u;
    #pragma unroll
    for (int off = 1; off < 64; off <<= 1) {
      unsigned o = __shfl_up(cum2, off);
      if (lane >= off) cum2 += o;
    }
    int crit2 = __popcll(__ballot(lane < NBUCK && cum2 < KK));   // <= 55 (>=20 pts have bk<56)
    unsigned cnew = __shfl(cum2, crit2);
    if (cnew <= CAP) {
      // final collect: accept bk <= crit2, bit-identical quantization to the hist pass
      cnt = 0;
      for (int j0 = rlo; j0 < rhi; j0 += 64) {
        int j = j0 + lane;
        bool acc = false; float d = 0.f;
        if (j < rhi) {
          float4 p = sxb[j];
          float inner = fmaf(p.x, me.x, fmaf(p.y, me.y, p.z * me.z));
          d = fmaf(-2.0f, inner, me.w + p.w);
          int bk = (int)(d * s56);
          acc = bk <= crit2;
        }
        unsigned long long m = __ballot(acc);
        if (acc) {
          int slot = cnt + __popcll(m & below);
          if (slot < CAP) {
            int bb = (int)__float_as_uint(d);
            unsigned sk = (unsigned)(bb ^ ((bb >> 31) | 0x80000000));
            cdk[wid][slot] = ((unsigned long long)sk << 32) | (unsigned)ordb[j];
          }
        }
        cnt += __popcll(m);
      }
      break;                                   // cnt == cnew <= CAP
    }
    // tighten: new Tup = upper edge of crit2 bucket (valid: >=20 pts with d < it); shrink window
    Tup = (float)(crit2 + 1) * (Tup / 56.0f);
    rT = sqrtf(Tup);
    bn_ = (int)((me.x - rT - 1e-5f + XOFF) * XSCALE);
    bn_ = bn_ < 0 ? 0 : (bn_ > XBINS - 1 ? XBINS - 1 : bn_);
    rlo = cumb[bn_];
    bn_ = (int)((me.x + rT + 1e-5f + XOFF) * XSCALE);
    bn_ = bn_ < 0 ? 0 : (bn_ > XBINS - 1 ? XBINS - 1 : bn_);
    rhi = cumb[bn_ + 1];
    cnt = (int)cnew;                           // still > CAP -> next iteration
  }

  const int nOrig = ordb[r];
  int* op = idx_out + (b * Nn + nOrig) * KK;

  if (cnt <= CAP) {
    // ---- P3: rank selection over cnt keys (distinct via orig idx; (d,idx)-lex == top_k) ----
    for (int c = lane; c < cnt; c += 64) {
      unsigned long long key = cdk[wid][c];
      int rank = 0;
      for (int c2 = 0; c2 < cnt; ++c2) rank += (cdk[wid][c2] < key) ? 1 : 0;
      if (rank < KK) op[rank] = (int)(key & 0xFFFFFFFFu);
    }
  } else {
    // ---- ultimate exact path: 20 rounds of wave-min, strictly-increasing keys ----
    unsigned long long last = 0ull;
    for (int k = 0; k < KK; ++k) {
      unsigned long long best = ~0ull;
      for (int j0 = rlo; j0 < rhi; j0 += 64) {
        int j = j0 + lane;
        if (j < rhi) {
          float4 p = sxb[j];
          float inner = fmaf(p.x, me.x, fmaf(p.y, me.y, p.z * me.z));
          float d = fmaf(-2.0f, inner, me.w + p.w);
          int bb = (int)__float_as_uint(d);
          unsigned sk = (unsigned)(bb ^ ((bb >> 31) | 0x80000000));
          unsigned long long key = ((unsigned long long)sk << 32) | (unsigned)ordb[j];
          if (key > last && key < best) best = key;
        }
      }
      #pragma unroll
      for (int off = 32; off >= 1; off >>= 1) {
        unsigned lo_ = (unsigned)best, hi_ = (unsigned)(best >> 32);
        unsigned olo = __shfl_xor(lo_, off), ohi = __shfl_xor(hi_, off);
        unsigned long long o = ((unsigned long long)ohi << 32) | olo;
        if (o < best) best = o;
      }
      if (lane == 0) op[k] = (int)(best & 0xFFFFFFFFu);
      last = best;
    }
  }
}

// ---------------- u = (Wa-Wb)·x_n, v = Wb·x_n  (layout [b][n][o], o contiguous) -------------

__global__ __launch_bounds__(256) void uv_kernel(const float* __restrict__ x,
                                                 const float* __restrict__ W,
                                                 float* __restrict__ u,
                                                 float* __restrict__ v) {
  int gid = blockIdx.x * 256 + threadIdx.x;
  int o  = gid & 63;
  int bn = gid >> 6;
  int b  = bn >> 13;
  int n  = bn & (Nn - 1);
  const float* xb = x + b * 3 * Nn;
  float x0 = xb[n], x1 = xb[Nn + n], x2 = xb[2 * Nn + n];
  float wa0 = W[o * 6 + 0], wa1 = W[o * 6 + 1], wa2 = W[o * 6 + 2];
  float wb0 = W[o * 6 + 3], wb1 = W[o * 6 + 4], wb2 = W[o * 6 + 5];
  u[gid] = (wa0 - wb0) * x0 + (wa1 - wb1) * x1 + (wa2 - wb2) * x2;
  v[gid] = wb0 * x0 + wb1 * x1 + wb2 * x2;
}

// ---------------- gather v over neighbors: pm = u + max_k v ; accumulate S1,S2 --------------

__global__ __launch_bounds__(256) void gather_kernel(const int* __restrict__ idx,
                                                     float* __restrict__ u,      // in-place -> pm
                                                     const float* __restrict__ v,
                                                     float* __restrict__ stats) {
  __shared__ float ls1[4][64], ls2[4][64];
  int b  = blockIdx.y;
  int o  = threadIdx.x & 63;
  int ys = threadIdx.x >> 6;
  const float* vb = v + (size_t)b * Nn * OO;
  float s1 = 0.f, s2 = 0.f;
  for (int i = 0; i < 16; ++i) {
    int n = blockIdx.x * 64 + ys * 16 + i;
    const int* ip = idx + (b * Nn + n) * KK;
    float un = u[(size_t)(b * Nn + n) * OO + o];
    float sv = 0.f, sv2 = 0.f, mv = -__builtin_inff();
    #pragma unroll
    for (int k = 0; k < KK; ++k) {
      int j = ip[k];
      float val = vb[(size_t)j * OO + o];
      sv += val; sv2 += val * val; mv = fmaxf(mv, val);
    }
    u[(size_t)(b * Nn + n) * OO + o] = un + mv;
    s1 += (float)KK * un + sv;
    s2 += (float)KK * un * un + 2.f * un * sv + sv2;
  }
  ls1[ys][o] = s1; ls2[ys][o] = s2;
  __syncthreads();
  if (ys == 0) {
    float t1 = ls1[0][o] + ls1[1][o] + ls1[2][o] + ls1[3][o];
    float t2 = ls2[0][o] + ls2[1][o] + ls2[2][o] + ls2[3][o];
    atomicAdd(&stats[(b * OO + o) * 2 + 0], t1);
    atomicAdd(&stats[(b * OO + o) * 2 + 1], t2);
  }
}

// ---------------- finalize: normalize + lrelu + transpose to [b][o][n] ----------------------

__global__ __launch_bounds__(256) void out_kernel(const float* __restrict__ pm,
                                                  const float* __restrict__ stats,
                                                  float* __restrict__ out) {
  __shared__ float tile[64][65];
  int b  = blockIdx.y;
  int o  = threadIdx.x & 63;
  int ys = threadIdx.x >> 6;
  const float inv_cnt = 1.0f / (float)(Nn * KK);
  float S1 = stats[(b * OO + o) * 2 + 0];
  float S2 = stats[(b * OO + o) * 2 + 1];
  float mean = S1 * inv_cnt;
  float var  = S2 * inv_cnt - mean * mean;
  float istd = rsqrtf(var + EPSF);
  for (int i = 0; i < 16; ++i) {
    int n = blockIdx.x * 64 + ys * 16 + i;
    float val = (pm[(size_t)(b * Nn + n) * OO + o] - mean) * istd;
    val = (val >= 0.f) ? val : SLOPEF * val;
    tile[ys * 16 + i][o] = val;
  }
  __syncthreads();
  int nb = blockIdx.x * 64;
  for (int i = 0; i < 16; ++i) {
    int oo = ys * 16 + i;
    out[(size_t)(b * OO + oo) * Nn + nb + o] = tile[o][oo];
  }
}

// ---------------- launch ---------------------------------------------------------------------

extern "C" void kernel_launch(void* const* d_in, const int* in_sizes, int n_in,
                              void* d_out, int out_size, void* d_ws, size_t ws_size,
                              hipStream_t stream) {
  const float* x = (const float*)d_in[0];
  const float* W = (const float*)d_in[1];
  float* out = (float*)d_out;

  char* ws = (char*)d_ws;
  int*    idx   = (int*)ws;                         // 2,621,440 B
  float*  u     = (float*)(ws + 2621440);           // 8,388,608 B (becomes pm)
  float*  v     = (float*)(ws + 11010048);          // 8,388,608 B
  float*  stats = (float*)(ws + 19398656);          // 4,096 B
  float4* sx    = (float4*)(ws + 19402752);         // 524,288 B (16B aligned)
  int*    ord   = (int*)(ws + 19927040);            // 131,072 B
  int*    cumg  = (int*)(ws + 20058112);            // 4,112 B

  hipMemsetAsync(stats, 0, Bb * OO * 2 * sizeof(float), stream);
  sort_kernel  <<<Bb, 1024, 0, stream>>>(x, sx, ord, cumg);
  uv_kernel    <<<dim3((Bb * Nn * OO) / 256), 256, 0, stream>>>(x, W, u, v);
  knn_kernel   <<<dim3(Nn / 16, Bb), 1024, 0, stream>>>(sx, ord, cumg, idx);
  gather_kernel<<<dim3(128, Bb), 256, 0, stream>>>(idx, u, v, stats);
  out_kernel   <<<dim3(128, Bb), 256, 0, stream>>>(u, stats, out);
}

// Round 11
// 237.381 us; speedup vs baseline: 14.9192x; 1.0745x over previous
//
#include <hip/hip_runtime.h>

#define Nn 8192
#define Bb 4
#define KK 20
#define OO 64
#define EPSF 1e-5f
#define SLOPEF 0.2f

#define NBUCK 56
#define CAP 256               // per-row candidate list; refine loop handles overflow
#define BOFF 476              // (bits(2^-8) >> 21)
#define CLO 0.00390625f       // 2^-8
#define CHI 63.9999961853f    // largest float < 64 -> coarse bucket <= 55
#define XBINS 256
#define XSCALE 25.6f          // bins over x in [-5, 5]
#define XOFF 5.0f

// ---------------- counting sort by x-bin: sx (sorted float4), ord (sorted->orig), cum -------

__global__ __launch_bounds__(1024) void sort_kernel(const float* __restrict__ x,
                                                    float4* __restrict__ sx,
                                                    int* __restrict__ ord,
                                                    int* __restrict__ cumg) {
  __shared__ unsigned hcnt[XBINS];
  __shared__ unsigned base[XBINS];
  __shared__ unsigned char binb[Nn];
  const int b = blockIdx.x;
  const float* xb = x + b * 3 * Nn;
  for (int t = threadIdx.x; t < XBINS; t += 1024) hcnt[t] = 0u;
  __syncthreads();
  for (int j = threadIdx.x; j < Nn; j += 1024) {
    float a0 = xb[j];
    int bin = (int)((a0 + XOFF) * XSCALE);               // monotone in x
    bin = bin < 0 ? 0 : (bin > XBINS - 1 ? XBINS - 1 : bin);
    binb[j] = (unsigned char)bin;
    atomicAdd(&hcnt[bin], 1u);
  }
  __syncthreads();
  if (threadIdx.x == 0) {
    unsigned run = 0;
    #pragma unroll 8
    for (int i = 0; i < XBINS; ++i) {
      base[i] = run;
      cumg[b * (XBINS + 1) + i] = (int)run;
      run += hcnt[i];
    }
    cumg[b * (XBINS + 1) + XBINS] = (int)run;            // = 8192
  }
  __syncthreads();
  for (int j = threadIdx.x; j < Nn; j += 1024) {
    float a0 = xb[j], a1 = xb[Nn + j], a2 = xb[2 * Nn + j];
    unsigned slot = atomicAdd(&base[binb[j]], 1u);       // in-bin order arbitrary (keys carry
    sx[b * Nn + slot] = make_float4(a0, a1, a2, a0 * a0 + a1 * a1 + a2 * a2);
    ord[b * Nn + slot] = j;                              //  orig idx -> order-independent)
  }
}

// ---------------- KNN: exact top-20, ROW-PER-WAVE, x-window + histogram refinement ----------
// Wave = one sorted row, r = wid*512 + blockIdx.x (STRIDED: each block's 16 rows spread
// uniformly over the sorted order -> balanced block runtimes). No __syncthreads; per-wave
// LDS slices. Candidate append is ORDER-FREE (P3 rank-selects by key): slot via per-wave
// LDS atomicAdd -> loop iterations independent (ILP), no ballot chain. Exactness as R10:
// subset-hist upper bound Tup; window provably superset (d >= dx^2, eps=1e-5 slack);
// refine loop on overflow (monotone quantized accept, bit-identical recompute); ultimate
// 20-round wave-min path. All paths exact; output deterministic (keys distinct via orig idx).

__global__ __launch_bounds__(1024, 8) void knn_kernel(const float4* __restrict__ sx,
                                                      const int* __restrict__ ord,
                                                      const int* __restrict__ cumg,
                                                      int* __restrict__ idx_out) {
  __shared__ unsigned hist[16][64];                 //  4096 B, per-wave slice
  __shared__ unsigned long long cdk[16][CAP];       // 32768 B, per-wave slice
  __shared__ unsigned ccnt[16];

  const int lane = threadIdx.x & 63;
  const int wid  = threadIdx.x >> 6;
  const int b    = blockIdx.y;
  const int r    = (wid << 9) + blockIdx.x;         // strided row spread (wave-uniform)

  const float4* __restrict__ sxb  = sx + b * Nn;
  const int*    __restrict__ ordb = ord + b * Nn;
  const int*    __restrict__ cumb = cumg + b * (XBINS + 1);
  const float4 me = sxb[r];

  hist[wid][lane] = 0u;
  if (lane == 0) ccnt[wid] = 0u;

  // ---- P1: coarse hist of 512 x-near points ----
  int sub0 = r - 256; sub0 = sub0 < 0 ? 0 : (sub0 > Nn - 512 ? Nn - 512 : sub0);
  #pragma unroll
  for (int i = 0; i < 8; ++i) {
    float4 p = sxb[sub0 + i * 64 + lane];
    float inner = fmaf(p.x, me.x, fmaf(p.y, me.y, p.z * me.z));
    float d  = fmaf(-2.0f, inner, me.w + p.w);
    float dc = __builtin_amdgcn_fmed3f(d, CLO, CHI);
    atomicAdd(&hist[wid][(__float_as_uint(dc) >> 21) - BOFF], 1u);
  }
  // wave prefix-scan of the 56 buckets
  unsigned cum = (lane < NBUCK) ? hist[wid][lane] : 0u;
  #pragma unroll
  for (int off = 1; off < 64; off <<= 1) {
    unsigned o = __shfl_up(cum, off);
    if (lane >= off) cum += o;
  }
  int crit = __popcll(__ballot(lane < NBUCK && cum < KK));
  // crit>=55: bucket-55 holds clamped d>CHI -> invalid edge; fall back to huge Tup
  float Tup = (crit >= NBUCK - 1) ? 256.0f
                                  : __uint_as_float((unsigned)(BOFF + crit + 1) << 21);

  // ---- window from Tup (superset-safe: absolute 1e-5 slack > all rounding) ----
  float rT = sqrtf(Tup);
  int bn_ = (int)((me.x - rT - 1e-5f + XOFF) * XSCALE);
  bn_ = bn_ < 0 ? 0 : (bn_ > XBINS - 1 ? XBINS - 1 : bn_);
  int rlo = cumb[bn_];
  bn_ = (int)((me.x + rT + 1e-5f + XOFF) * XSCALE);
  bn_ = bn_ < 0 ? 0 : (bn_ > XBINS - 1 ? XBINS - 1 : bn_);
  int rhi = cumb[bn_ + 1];

  // ---- pass 1: collect d < Tup, order-free atomic append (independent iterations) ----
  for (int j0 = rlo; j0 < rhi; j0 += 128) {
    #pragma unroll
    for (int t = 0; t < 2; ++t) {
      int j = j0 + t * 64 + lane;
      if (j < rhi) {
        float4 p = sxb[j];
        float inner = fmaf(p.x, me.x, fmaf(p.y, me.y, p.z * me.z));
        float d = fmaf(-2.0f, inner, me.w + p.w);
        if (d < Tup) {
          int bb = (int)__float_as_uint(d);
          unsigned sk = (unsigned)(bb ^ ((bb >> 31) | 0x80000000));
          unsigned c = atomicAdd(&ccnt[wid], 1u);
          if (c < CAP)
            cdk[wid][c] = ((unsigned long long)sk << 32) | (unsigned)ordb[j];
        }
      }
    }
  }
  int cnt = (int)ccnt[wid];                 // same-wave DS ordering -> all appends visible

  // ---- refine loop (rare: y,z-outlier rows where slab Tup is loose) ----
  for (int it = 0; cnt > CAP && it < 4; ++it) {
    hist[wid][lane] = 0u;
    const float s56 = 56.0f / Tup;
    for (int j0 = rlo; j0 < rhi; j0 += 64) {
      int j = j0 + lane;
      if (j < rhi) {
        float4 p = sxb[j];
        float inner = fmaf(p.x, me.x, fmaf(p.y, me.y, p.z * me.z));
        float d = fmaf(-2.0f, inner, me.w + p.w);
        int bk = (int)(d * s56);              // d<0 (self, fp) -> 0 via trunc
        if ((unsigned)bk < (unsigned)NBUCK) atomicAdd(&hist[wid][bk], 1u);
      }
    }
    unsigned cum2 = (lane < NBUCK) ? hist[wid][lane] : 0u;
    #pragma unroll
    for (int off = 1; off < 64; off <<= 1) {
      unsigned o = __shfl_up(cum2, off);
      if (lane >= off) cum2 += o;
    }
    int crit2 = __popcll(__ballot(lane < NBUCK && cum2 < KK));   // <= 55 (>=20 pts have bk<56)
    unsigned cnew = __shfl(cum2, crit2);
    if (cnew <= CAP) {
      // final collect: accept bk <= crit2, bit-identical quantization to the hist pass
      if (lane == 0) ccnt[wid] = 0u;
      for (int j0 = rlo; j0 < rhi; j0 += 64) {
        int j = j0 + lane;
        if (j < rhi) {
          float4 p = sxb[j];
          float inner = fmaf(p.x, me.x, fmaf(p.y, me.y, p.z * me.z));
          float d = fmaf(-2.0f, inner, me.w + p.w);
          int bk = (int)(d * s56);
          if (bk <= crit2) {
            int bb = (int)__float_as_uint(d);
            unsigned sk = (unsigned)(bb ^ ((bb >> 31) | 0x80000000));
            unsigned c = atomicAdd(&ccnt[wid], 1u);
            if (c < CAP)
              cdk[wid][c] = ((unsigned long long)sk << 32) | (unsigned)ordb[j];
          }
        }
      }
      cnt = (int)ccnt[wid];                  // == cnew <= CAP
      break;
    }
    // tighten: new Tup = upper edge of crit2 bucket (valid: >=20 pts below it); shrink window
    Tup = (float)(crit2 + 1) * (Tup / 56.0f);
    rT = sqrtf(Tup);
    bn_ = (int)((me.x - rT - 1e-5f + XOFF) * XSCALE);
    bn_ = bn_ < 0 ? 0 : (bn_ > XBINS - 1 ? XBINS - 1 : bn_);
    rlo = cumb[bn_];
    bn_ = (int)((me.x + rT + 1e-5f + XOFF) * XSCALE);
    bn_ = bn_ < 0 ? 0 : (bn_ > XBINS - 1 ? XBINS - 1 : bn_);
    rhi = cumb[bn_ + 1];
    cnt = (int)cnew;                         // still > CAP -> next iteration
  }

  const int nOrig = ordb[r];
  int* op = idx_out + (b * Nn + nOrig) * KK;

  if (cnt <= CAP) {
    // ---- P3: rank selection over cnt keys (distinct via orig idx; (d,idx)-lex == top_k) ----
    for (int c = lane; c < cnt; c += 64) {
      unsigned long long key = cdk[wid][c];
      int rank = 0;
      for (int c2 = 0; c2 < cnt; ++c2) rank += (cdk[wid][c2] < key) ? 1 : 0;
      if (rank < KK) op[rank] = (int)(key & 0xFFFFFFFFu);
    }
  } else {
    // ---- ultimate exact path: 20 rounds of wave-min, strictly-increasing keys ----
    unsigned long long last = 0ull;
    for (int k = 0; k < KK; ++k) {
      unsigned long long best = ~0ull;
      for (int j0 = rlo; j0 < rhi; j0 += 64) {
        int j = j0 + lane;
        if (j < rhi) {
          float4 p = sxb[j];
          float inner = fmaf(p.x, me.x, fmaf(p.y, me.y, p.z * me.z));
          float d = fmaf(-2.0f, inner, me.w + p.w);
          int bb = (int)__float_as_uint(d);
          unsigned sk = (unsigned)(bb ^ ((bb >> 31) | 0x80000000));
          unsigned long long key = ((unsigned long long)sk << 32) | (unsigned)ordb[j];
          if (key > last && key < best) best = key;
        }
      }
      #pragma unroll
      for (int off = 32; off >= 1; off >>= 1) {
        unsigned lo_ = (unsigned)best, hi_ = (unsigned)(best >> 32);
        unsigned olo = __shfl_xor(lo_, off), ohi = __shfl_xor(hi_, off);
        unsigned long long o = ((unsigned long long)ohi << 32) | olo;
        if (o < best) best = o;
      }
      if (lane == 0) op[k] = (int)(best & 0xFFFFFFFFu);
      last = best;
    }
  }
}

// ---------------- u = (Wa-Wb)·x_n, v = Wb·x_n  (layout [b][n][o], o contiguous) -------------

__global__ __launch_bounds__(256) void uv_kernel(const float* __restrict__ x,
                                                 const float* __restrict__ W,
                                                 float* __restrict__ u,
                                                 float* __restrict__ v) {
  int gid = blockIdx.x * 256 + threadIdx.x;
  int o  = gid & 63;
  int bn = gid >> 6;
  int b  = bn >> 13;
  int n  = bn & (Nn - 1);
  const float* xb = x + b * 3 * Nn;
  float x0 = xb[n], x1 = xb[Nn + n], x2 = xb[2 * Nn + n];
  float wa0 = W[o * 6 + 0], wa1 = W[o * 6 + 1], wa2 = W[o * 6 + 2];
  float wb0 = W[o * 6 + 3], wb1 = W[o * 6 + 4], wb2 = W[o * 6 + 5];
  u[gid] = (wa0 - wb0) * x0 + (wa1 - wb1) * x1 + (wa2 - wb2) * x2;
  v[gid] = wb0 * x0 + wb1 * x1 + wb2 * x2;
}

// ---------------- gather v over neighbors: pm = u + max_k v ; accumulate S1,S2 --------------

__global__ __launch_bounds__(256) void gather_kernel(const int* __restrict__ idx,
                                                     float* __restrict__ u,      // in-place -> pm
                                                     const float* __restrict__ v,
                                                     float* __restrict__ stats) {
  __shared__ float ls1[4][64], ls2[4][64];
  int b  = blockIdx.y;
  int o  = threadIdx.x & 63;
  int ys = threadIdx.x >> 6;
  const float* vb = v + (size_t)b * Nn * OO;
  float s1 = 0.f, s2 = 0.f;
  for (int i = 0; i < 16; ++i) {
    int n = blockIdx.x * 64 + ys * 16 + i;
    const int* ip = idx + (b * Nn + n) * KK;
    float un = u[(size_t)(b * Nn + n) * OO + o];
    float sv = 0.f, sv2 = 0.f, mv = -__builtin_inff();
    #pragma unroll
    for (int k = 0; k < KK; ++k) {
      int j = ip[k];
      float val = vb[(size_t)j * OO + o];
      sv += val; sv2 += val * val; mv = fmaxf(mv, val);
    }
    u[(size_t)(b * Nn + n) * OO + o] = un + mv;
    s1 += (float)KK * un + sv;
    s2 += (float)KK * un * un + 2.f * un * sv + sv2;
  }
  ls1[ys][o] = s1; ls2[ys][o] = s2;
  __syncthreads();
  if (ys == 0) {
    float t1 = ls1[0][o] + ls1[1][o] + ls1[2][o] + ls1[3][o];
    float t2 = ls2[0][o] + ls2[1][o] + ls2[2][o] + ls2[3][o];
    atomicAdd(&stats[(b * OO + o) * 2 + 0], t1);
    atomicAdd(&stats[(b * OO + o) * 2 + 1], t2);
  }
}

// ---------------- finalize: normalize + lrelu + transpose to [b][o][n] ----------------------

__global__ __launch_bounds__(256) void out_kernel(const float* __restrict__ pm,
                                                  const float* __restrict__ stats,
                                                  float* __restrict__ out) {
  __shared__ float tile[64][65];
  int b  = blockIdx.y;
  int o  = threadIdx.x & 63;
  int ys = threadIdx.x >> 6;
  const float inv_cnt = 1.0f / (float)(Nn * KK);
  float S1 = stats[(b * OO + o) * 2 + 0];
  float S2 = stats[(b * OO + o) * 2 + 1];
  float mean = S1 * inv_cnt;
  float var  = S2 * inv_cnt - mean * mean;
  float istd = rsqrtf(var + EPSF);
  for (int i = 0; i < 16; ++i) {
    int n = blockIdx.x * 64 + ys * 16 + i;
    float val = (pm[(size_t)(b * Nn + n) * OO + o] - mean) * istd;
    val = (val >= 0.f) ? val : SLOPEF * val;
    tile[ys * 16 + i][o] = val;
  }
  __syncthreads();
  int nb = blockIdx.x * 64;
  for (int i = 0; i < 16; ++i) {
    int oo = ys * 16 + i;
    out[(size_t)(b * OO + oo) * Nn + nb + o] = tile[o][oo];
  }
}

// ---------------- launch ---------------------------------------------------------------------

extern "C" void kernel_launch(void* const* d_in, const int* in_sizes, int n_in,
                              void* d_out, int out_size, void* d_ws, size_t ws_size,
                              hipStream_t stream) {
  const float* x = (const float*)d_in[0];
  const float* W = (const float*)d_in[1];
  float* out = (float*)d_out;

  char* ws = (char*)d_ws;
  int*    idx   = (int*)ws;                         // 2,621,440 B
  float*  u     = (float*)(ws + 2621440);           // 8,388,608 B (becomes pm)
  float*  v     = (float*)(ws + 11010048);          // 8,388,608 B
  float*  stats = (float*)(ws + 19398656);          // 4,096 B
  float4* sx    = (float4*)(ws + 19402752);         // 524,288 B (16B aligned)
  int*    ord   = (int*)(ws + 19927040);            // 131,072 B
  int*    cumg  = (int*)(ws + 20058112);            // 4,112 B

  hipMemsetAsync(stats, 0, Bb * OO * 2 * sizeof(float), stream);
  sort_kernel  <<<Bb, 1024, 0, stream>>>(x, sx, ord, cumg);
  uv_kernel    <<<dim3((Bb * Nn * OO) / 256), 256, 0, stream>>>(x, W, u, v);
  knn_kernel   <<<dim3(Nn / 16, Bb), 1024, 0, stream>>>(sx, ord, cumg, idx);
  gather_kernel<<<dim3(128, Bb), 256, 0, stream>>>(idx, u, v, stats);
  out_kernel   <<<dim3(128, Bb), 256, 0, stream>>>(u, stats, out);
}

// Round 12
// 217.079 us; speedup vs baseline: 16.3145x; 1.0935x over previous
//
#include <hip/hip_runtime.h>

#define Nn 8192
#define Bb 4
#define KK 20
#define OO 64
#define EPSF 1e-5f
#define SLOPEF 0.2f

#define NBUCK 56
#define CAP 256               // per-row candidate list; refine loop handles overflow
#define BOFF 476              // (bits(2^-8) >> 21)
#define CLO 0.00390625f       // 2^-8
#define CHI 63.9999961853f    // largest float < 64 -> coarse bucket <= 55
#define XBINS 256
#define XSCALE 25.6f          // bins over x in [-5, 5]
#define XOFF 5.0f

// ---------------- counting sort by x-bin: sx (sorted float4), ord (sorted->orig), cum -------

__global__ __launch_bounds__(1024) void sort_kernel(const float* __restrict__ x,
                                                    float4* __restrict__ sx,
                                                    int* __restrict__ ord,
                                                    int* __restrict__ cumg) {
  __shared__ unsigned hcnt[XBINS];
  __shared__ unsigned base[XBINS];
  __shared__ unsigned char binb[Nn];
  const int b = blockIdx.x;
  const float* xb = x + b * 3 * Nn;
  for (int t = threadIdx.x; t < XBINS; t += 1024) hcnt[t] = 0u;
  __syncthreads();
  for (int j = threadIdx.x; j < Nn; j += 1024) {
    float a0 = xb[j];
    int bin = (int)((a0 + XOFF) * XSCALE);               // monotone in x
    bin = bin < 0 ? 0 : (bin > XBINS - 1 ? XBINS - 1 : bin);
    binb[j] = (unsigned char)bin;
    atomicAdd(&hcnt[bin], 1u);
  }
  __syncthreads();
  if (threadIdx.x == 0) {
    unsigned run = 0;
    #pragma unroll 8
    for (int i = 0; i < XBINS; ++i) {
      base[i] = run;
      cumg[b * (XBINS + 1) + i] = (int)run;
      run += hcnt[i];
    }
    cumg[b * (XBINS + 1) + XBINS] = (int)run;            // = 8192
  }
  __syncthreads();
  for (int j = threadIdx.x; j < Nn; j += 1024) {
    float a0 = xb[j], a1 = xb[Nn + j], a2 = xb[2 * Nn + j];
    unsigned slot = atomicAdd(&base[binb[j]], 1u);       // in-bin order arbitrary (keys carry
    sx[b * Nn + slot] = make_float4(a0, a1, a2, a0 * a0 + a1 * a1 + a2 * a2);
    ord[b * Nn + slot] = j;                              //  orig idx -> order-independent)
  }
}

// ---------------- KNN: exact top-20, ROW-PER-WAVE, x-window + histogram refinement ----------
// 256-thread blocks (4 waves) -> 8 independent blocks/CU at the 32-wave slot limit: fine
// scheduling quanta, tail of a slow wave only holds 4 waves' LDS, idle slots backfilled.
// Wave = one sorted row, r = wid*2048 + blockIdx.x (strided -> balanced). No __syncthreads;
// per-wave LDS slices; candidate append order-free via per-wave atomic (P3 rank-selects by
// key). Exactness: subset-hist upper bound Tup; window superset (d >= dx^2, eps slack);
// refine loop on overflow (monotone quantized accept, bit-identical recompute); ultimate
// 20-round wave-min path. All paths exact; deterministic (keys distinct via orig idx).

__global__ __launch_bounds__(256, 8) void knn_kernel(const float4* __restrict__ sx,
                                                     const int* __restrict__ ord,
                                                     const int* __restrict__ cumg,
                                                     int* __restrict__ idx_out) {
  __shared__ unsigned hist[4][64];                  //  1024 B, per-wave slice
  __shared__ unsigned long long cdk[4][CAP];        //  8192 B, per-wave slice
  __shared__ unsigned ccnt[4];

  const int lane = threadIdx.x & 63;
  const int wid  = threadIdx.x >> 6;
  const int b    = blockIdx.y;
  const int r    = (wid << 11) + blockIdx.x;        // strided row spread (wave-uniform)

  const float4* __restrict__ sxb  = sx + b * Nn;
  const int*    __restrict__ ordb = ord + b * Nn;
  const int*    __restrict__ cumb = cumg + b * (XBINS + 1);
  const float4 me = sxb[r];

  hist[wid][lane] = 0u;
  if (lane == 0) ccnt[wid] = 0u;

  // ---- P1: coarse hist of 512 x-near points ----
  int sub0 = r - 256; sub0 = sub0 < 0 ? 0 : (sub0 > Nn - 512 ? Nn - 512 : sub0);
  #pragma unroll
  for (int i = 0; i < 8; ++i) {
    float4 p = sxb[sub0 + i * 64 + lane];
    float inner = fmaf(p.x, me.x, fmaf(p.y, me.y, p.z * me.z));
    float d  = fmaf(-2.0f, inner, me.w + p.w);
    float dc = __builtin_amdgcn_fmed3f(d, CLO, CHI);
    atomicAdd(&hist[wid][(__float_as_uint(dc) >> 21) - BOFF], 1u);
  }
  // wave prefix-scan of the 56 buckets
  unsigned cum = (lane < NBUCK) ? hist[wid][lane] : 0u;
  #pragma unroll
  for (int off = 1; off < 64; off <<= 1) {
    unsigned o = __shfl_up(cum, off);
    if (lane >= off) cum += o;
  }
  int crit = __popcll(__ballot(lane < NBUCK && cum < KK));
  // crit>=55: bucket-55 holds clamped d>CHI -> invalid edge; fall back to huge Tup
  float Tup = (crit >= NBUCK - 1) ? 256.0f
                                  : __uint_as_float((unsigned)(BOFF + crit + 1) << 21);

  // ---- window from Tup (superset-safe: absolute 1e-5 slack > all rounding) ----
  float rT = sqrtf(Tup);
  int bn_ = (int)((me.x - rT - 1e-5f + XOFF) * XSCALE);
  bn_ = bn_ < 0 ? 0 : (bn_ > XBINS - 1 ? XBINS - 1 : bn_);
  int rlo = cumb[bn_];
  bn_ = (int)((me.x + rT + 1e-5f + XOFF) * XSCALE);
  bn_ = bn_ < 0 ? 0 : (bn_ > XBINS - 1 ? XBINS - 1 : bn_);
  int rhi = cumb[bn_ + 1];

  // ---- pass 1: collect d < Tup, order-free atomic append; 4x unroll for load ILP ----
  for (int j0 = rlo; j0 < rhi; j0 += 256) {
    #pragma unroll
    for (int t = 0; t < 4; ++t) {
      int j = j0 + t * 64 + lane;
      if (j < rhi) {
        float4 p = sxb[j];
        float inner = fmaf(p.x, me.x, fmaf(p.y, me.y, p.z * me.z));
        float d = fmaf(-2.0f, inner, me.w + p.w);
        if (d < Tup) {
          int bb = (int)__float_as_uint(d);
          unsigned sk = (unsigned)(bb ^ ((bb >> 31) | 0x80000000));
          unsigned c = atomicAdd(&ccnt[wid], 1u);
          if (c < CAP)
            cdk[wid][c] = ((unsigned long long)sk << 32) | (unsigned)ordb[j];
        }
      }
    }
  }
  int cnt = (int)ccnt[wid];                 // same-wave DS ordering -> all appends visible

  // ---- refine loop (rare: y,z-outlier rows where slab Tup is loose) ----
  for (int it = 0; cnt > CAP && it < 4; ++it) {
    hist[wid][lane] = 0u;
    const float s56 = 56.0f / Tup;
    for (int j0 = rlo; j0 < rhi; j0 += 64) {
      int j = j0 + lane;
      if (j < rhi) {
        float4 p = sxb[j];
        float inner = fmaf(p.x, me.x, fmaf(p.y, me.y, p.z * me.z));
        float d = fmaf(-2.0f, inner, me.w + p.w);
        int bk = (int)(d * s56);              // d<0 (self, fp) -> 0 via trunc
        if ((unsigned)bk < (unsigned)NBUCK) atomicAdd(&hist[wid][bk], 1u);
      }
    }
    unsigned cum2 = (lane < NBUCK) ? hist[wid][lane] : 0u;
    #pragma unroll
    for (int off = 1; off < 64; off <<= 1) {
      unsigned o = __shfl_up(cum2, off);
      if (lane >= off) cum2 += o;
    }
    int crit2 = __popcll(__ballot(lane < NBUCK && cum2 < KK));   // <= 55 (>=20 pts have bk<56)
    unsigned cnew = __shfl(cum2, crit2);
    if (cnew <= CAP) {
      // final collect: accept bk <= crit2, bit-identical quantization to the hist pass
      if (lane == 0) ccnt[wid] = 0u;
      for (int j0 = rlo; j0 < rhi; j0 += 64) {
        int j = j0 + lane;
        if (j < rhi) {
          float4 p = sxb[j];
          float inner = fmaf(p.x, me.x, fmaf(p.y, me.y, p.z * me.z));
          float d = fmaf(-2.0f, inner, me.w + p.w);
          int bk = (int)(d * s56);
          if (bk <= crit2) {
            int bb = (int)__float_as_uint(d);
            unsigned sk = (unsigned)(bb ^ ((bb >> 31) | 0x80000000));
            unsigned c = atomicAdd(&ccnt[wid], 1u);
            if (c < CAP)
              cdk[wid][c] = ((unsigned long long)sk << 32) | (unsigned)ordb[j];
          }
        }
      }
      cnt = (int)ccnt[wid];                  // == cnew <= CAP
      break;
    }
    // tighten: new Tup = upper edge of crit2 bucket (valid: >=20 pts below it); shrink window
    Tup = (float)(crit2 + 1) * (Tup / 56.0f);
    rT = sqrtf(Tup);
    bn_ = (int)((me.x - rT - 1e-5f + XOFF) * XSCALE);
    bn_ = bn_ < 0 ? 0 : (bn_ > XBINS - 1 ? XBINS - 1 : bn_);
    rlo = cumb[bn_];
    bn_ = (int)((me.x + rT + 1e-5f + XOFF) * XSCALE);
    bn_ = bn_ < 0 ? 0 : (bn_ > XBINS - 1 ? XBINS - 1 : bn_);
    rhi = cumb[bn_ + 1];
    cnt = (int)cnew;                         // still > CAP -> next iteration
  }

  const int nOrig = ordb[r];
  int* op = idx_out + (b * Nn + nOrig) * KK;

  if (cnt <= CAP) {
    // ---- P3: rank selection over cnt keys (distinct via orig idx; (d,idx)-lex == top_k) ----
    for (int c = lane; c < cnt; c += 64) {
      unsigned long long key = cdk[wid][c];
      int rank = 0;
      for (int c2 = 0; c2 < cnt; ++c2) rank += (cdk[wid][c2] < key) ? 1 : 0;
      if (rank < KK) op[rank] = (int)(key & 0xFFFFFFFFu);
    }
  } else {
    // ---- ultimate exact path: 20 rounds of wave-min, strictly-increasing keys ----
    unsigned long long last = 0ull;
    for (int k = 0; k < KK; ++k) {
      unsigned long long best = ~0ull;
      for (int j0 = rlo; j0 < rhi; j0 += 64) {
        int j = j0 + lane;
        if (j < rhi) {
          float4 p = sxb[j];
          float inner = fmaf(p.x, me.x, fmaf(p.y, me.y, p.z * me.z));
          float d = fmaf(-2.0f, inner, me.w + p.w);
          int bb = (int)__float_as_uint(d);
          unsigned sk = (unsigned)(bb ^ ((bb >> 31) | 0x80000000));
          unsigned long long key = ((unsigned long long)sk << 32) | (unsigned)ordb[j];
          if (key > last && key < best) best = key;
        }
      }
      #pragma unroll
      for (int off = 32; off >= 1; off >>= 1) {
        unsigned lo_ = (unsigned)best, hi_ = (unsigned)(best >> 32);
        unsigned olo = __shfl_xor(lo_, off), ohi = __shfl_xor(hi_, off);
        unsigned long long o = ((unsigned long long)ohi << 32) | olo;
        if (o < best) best = o;
      }
      if (lane == 0) op[k] = (int)(best & 0xFFFFFFFFu);
      last = best;
    }
  }
}

// ---------------- u = (Wa-Wb)·x_n, v = Wb·x_n  (layout [b][n][o], o contiguous) -------------

__global__ __launch_bounds__(256) void uv_kernel(const float* __restrict__ x,
                                                 const float* __restrict__ W,
                                                 float* __restrict__ u,
                                                 float* __restrict__ v) {
  int gid = blockIdx.x * 256 + threadIdx.x;
  int o  = gid & 63;
  int bn = gid >> 6;
  int b  = bn >> 13;
  int n  = bn & (Nn - 1);
  const float* xb = x + b * 3 * Nn;
  float x0 = xb[n], x1 = xb[Nn + n], x2 = xb[2 * Nn + n];
  float wa0 = W[o * 6 + 0], wa1 = W[o * 6 + 1], wa2 = W[o * 6 + 2];
  float wb0 = W[o * 6 + 3], wb1 = W[o * 6 + 4], wb2 = W[o * 6 + 5];
  u[gid] = (wa0 - wb0) * x0 + (wa1 - wb1) * x1 + (wa2 - wb2) * x2;
  v[gid] = wb0 * x0 + wb1 * x1 + wb2 * x2;
}

// ---------------- gather v over neighbors: pm = u + max_k v ; accumulate S1,S2 --------------

__global__ __launch_bounds__(256) void gather_kernel(const int* __restrict__ idx,
                                                     float* __restrict__ u,      // in-place -> pm
                                                     const float* __restrict__ v,
                                                     float* __restrict__ stats) {
  __shared__ float ls1[4][64], ls2[4][64];
  int b  = blockIdx.y;
  int o  = threadIdx.x & 63;
  int ys = threadIdx.x >> 6;
  const float* vb = v + (size_t)b * Nn * OO;
  float s1 = 0.f, s2 = 0.f;
  for (int i = 0; i < 16; ++i) {
    int n = blockIdx.x * 64 + ys * 16 + i;
    const int* ip = idx + (b * Nn + n) * KK;
    float un = u[(size_t)(b * Nn + n) * OO + o];
    float sv = 0.f, sv2 = 0.f, mv = -__builtin_inff();
    #pragma unroll
    for (int k = 0; k < KK; ++k) {
      int j = ip[k];
      float val = vb[(size_t)j * OO + o];
      sv += val; sv2 += val * val; mv = fmaxf(mv, val);
    }
    u[(size_t)(b * Nn + n) * OO + o] = un + mv;
    s1 += (float)KK * un + sv;
    s2 += (float)KK * un * un + 2.f * un * sv + sv2;
  }
  ls1[ys][o] = s1; ls2[ys][o] = s2;
  __syncthreads();
  if (ys == 0) {
    float t1 = ls1[0][o] + ls1[1][o] + ls1[2][o] + ls1[3][o];
    float t2 = ls2[0][o] + ls2[1][o] + ls2[2][o] + ls2[3][o];
    atomicAdd(&stats[(b * OO + o) * 2 + 0], t1);
    atomicAdd(&stats[(b * OO + o) * 2 + 1], t2);
  }
}

// ---------------- finalize: normalize + lrelu + transpose to [b][o][n] ----------------------

__global__ __launch_bounds__(256) void out_kernel(const float* __restrict__ pm,
                                                  const float* __restrict__ stats,
                                                  float* __restrict__ out) {
  __shared__ float tile[64][65];
  int b  = blockIdx.y;
  int o  = threadIdx.x & 63;
  int ys = threadIdx.x >> 6;
  const float inv_cnt = 1.0f / (float)(Nn * KK);
  float S1 = stats[(b * OO + o) * 2 + 0];
  float S2 = stats[(b * OO + o) * 2 + 1];
  float mean = S1 * inv_cnt;
  float var  = S2 * inv_cnt - mean * mean;
  float istd = rsqrtf(var + EPSF);
  for (int i = 0; i < 16; ++i) {
    int n = blockIdx.x * 64 + ys * 16 + i;
    float val = (pm[(size_t)(b * Nn + n) * OO + o] - mean) * istd;
    val = (val >= 0.f) ? val : SLOPEF * val;
    tile[ys * 16 + i][o] = val;
  }
  __syncthreads();
  int nb = blockIdx.x * 64;
  for (int i = 0; i < 16; ++i) {
    int oo = ys * 16 + i;
    out[(size_t)(b * OO + oo) * Nn + nb + o] = tile[o][oo];
  }
}

// ---------------- launch ---------------------------------------------------------------------

extern "C" void kernel_launch(void* const* d_in, const int* in_sizes, int n_in,
                              void* d_out, int out_size, void* d_ws, size_t ws_size,
                              hipStream_t stream) {
  const float* x = (const float*)d_in[0];
  const float* W = (const float*)d_in[1];
  float* out = (float*)d_out;

  char* ws = (char*)d_ws;
  int*    idx   = (int*)ws;                         // 2,621,440 B
  float*  u     = (float*)(ws + 2621440);           // 8,388,608 B (becomes pm)
  float*  v     = (float*)(ws + 11010048);          // 8,388,608 B
  float*  stats = (float*)(ws + 19398656);          // 4,096 B
  float4* sx    = (float4*)(ws + 19402752);         // 524,288 B (16B aligned)
  int*    ord   = (int*)(ws + 19927040);            // 131,072 B
  int*    cumg  = (int*)(ws + 20058112);            // 4,112 B

  hipMemsetAsync(stats, 0, Bb * OO * 2 * sizeof(float), stream);
  sort_kernel  <<<Bb, 1024, 0, stream>>>(x, sx, ord, cumg);
  uv_kernel    <<<dim3((Bb * Nn * OO) / 256), 256, 0, stream>>>(x, W, u, v);
  knn_kernel   <<<dim3(Nn / 4, Bb), 256, 0, stream>>>(sx, ord, cumg, idx);
  gather_kernel<<<dim3(128, Bb), 256, 0, stream>>>(idx, u, v, stats);
  out_kernel   <<<dim3(128, Bb), 256, 0, stream>>>(u, stats, out);
}